// Round 6
// baseline (186.204 us; speedup 1.0000x reference)
//
#include <hip/hip_runtime.h>

typedef __bf16 bf16x8 __attribute__((ext_vector_type(8)));
typedef __bf16 bf16x4 __attribute__((ext_vector_type(4)));
typedef float f32x4 __attribute__((ext_vector_type(4)));
typedef unsigned short u16;
typedef unsigned int u32;

static constexpr int kS = 2048, kD = 1024, kHD = 64;
// softmax scale (D^-0.5 = 1/32) * log2(e), folded into Q at projection time
static constexpr float kQScale = 0.03125f * 1.44269504f;

__device__ __forceinline__ u16 f2bf(float f) {
  union { float f; u32 u; } v; v.f = f;
  u32 r = v.u + 0x7FFFu + ((v.u >> 16) & 1u);
  return (u16)(r >> 16);
}
__device__ __forceinline__ float bf2f(u16 u) {
  union { u32 u; float f; } v; v.u = ((u32)u) << 16;
  return v.f;
}
__device__ __forceinline__ u32 pk2(float a, float b) {
  return (u32)f2bf(a) | ((u32)f2bf(b) << 16);
}
__device__ __forceinline__ f32x4 mfma16(bf16x8 a, bf16x8 b, f32x4 c) {
  return __builtin_amdgcn_mfma_f32_16x16x32_bf16(a, b, c, 0, 0, 0);
}
// async global->LDS, 16B per lane (m97 rung). LDS dest is wave-uniform base +
// lane*16 (UNPADDED [rows][64]); the GLOBAL source per lane is free, which is
// where the xor-swizzle lives (kills the 2x structural b128 read conflicts).
__device__ __forceinline__ void gld16(u16* lds, const u16* g) {
  __builtin_amdgcn_global_load_lds(
      (const __attribute__((address_space(1))) u32*)g,
      (__attribute__((address_space(3))) u32*)lds, 16, 0, 0);
}

// inline dtype probe: 256 samples of x as u16. fp32 bit patterns: the low-
// mantissa halves have uniform exponent fields -> ~47% read as |bf16|>=128;
// bf16 N(0,1) data: none. One load + one syncthreads_count per block.
__device__ __forceinline__ bool probe_f32(const u16* __restrict__ xr) {
  int ex = (xr[threadIdx.x] >> 7) & 0xFF;
  int n = __syncthreads_count(ex >= 134);
  return n > 8;
}

union Pack8 { u16 u[8]; uint4 v; };

// ---------- merged cast: Wt transpose always; Wp/x cast only in fp32 mode ----------
// bf16 mode: x and Wp are already in the exact layout the GEMMs stage from ->
// blocks 768+ exit (qkv/out read the originals directly; saves ~36MB r/w).
__global__ void cast_all_kernel(const void* Wq, const void* Wk, const void* Wv,
                                const void* Wp, const void* x,
                                u16* __restrict__ Wt, u16* __restrict__ Wpb,
                                u16* __restrict__ xb) {
  bool f32m = probe_f32((const u16*)x);
  int bid = blockIdx.x;
  int t = threadIdx.x;
  __shared__ float Ts[64][65];
  if (bid < 768) {
    // ---- W[h][d][e] -> Wt[(u*64+e)][d], u = which*16 + h ----
    int u = bid >> 4;
    int d0 = (bid & 15) * 64;
    int w = u >> 4, h = u & 15;
    const void* srcv = (w == 0) ? Wq : (w == 1) ? Wk : Wv;
    const float* sf = (const float*)srcv + (size_t)h * kD * kHD;
    const u16*   sb = (const u16*)srcv + (size_t)h * kD * kHD;
    int row = t >> 4;
    int c4 = (t & 15) * 4;
    for (int rr = 0; rr < 64; rr += 16) {
      int r = rr + row;
      if (f32m) {
        float4 v = *(const float4*)&sf[(size_t)(d0 + r) * kHD + c4];
        Ts[r][c4 + 0] = v.x; Ts[r][c4 + 1] = v.y; Ts[r][c4 + 2] = v.z; Ts[r][c4 + 3] = v.w;
      } else {
        const u16* p = &sb[(size_t)(d0 + r) * kHD + c4];
        Ts[r][c4 + 0] = bf2f(p[0]); Ts[r][c4 + 1] = bf2f(p[1]);
        Ts[r][c4 + 2] = bf2f(p[2]); Ts[r][c4 + 3] = bf2f(p[3]);
      }
    }
    __syncthreads();
    for (int rr = 0; rr < 64; rr += 16) {
      int e = rr + row;
      uint2 pk;
      pk.x = pk2(Ts[c4 + 0][e], Ts[c4 + 1][e]);
      pk.y = pk2(Ts[c4 + 2][e], Ts[c4 + 3][e]);
      *(uint2*)&Wt[(size_t)u * (kHD * kD) + (size_t)e * kD + d0 + c4] = pk;
    }
  } else if (bid < 1792) {
    if (!f32m) return;
    int i = ((bid - 768) * 256 + t) * 4;
    float4 v = *(const float4*)((const float*)Wp + i);
    uint2 pk; pk.x = pk2(v.x, v.y); pk.y = pk2(v.z, v.w);
    *(uint2*)&Wpb[i] = pk;
  } else {
    if (!f32m) return;
    size_t i = ((size_t)(bid - 1792) * 256 + t) * 8;
    const float* xf = (const float*)x;
    float4 a = *(const float4*)&xf[i];
    float4 b = *(const float4*)&xf[i + 4];
    Pack8 pk;
    pk.u[0] = f2bf(a.x); pk.u[1] = f2bf(a.y); pk.u[2] = f2bf(a.z); pk.u[3] = f2bf(a.w);
    pk.u[4] = f2bf(b.x); pk.u[5] = f2bf(b.y); pk.u[6] = f2bf(b.z); pk.u[7] = f2bf(b.w);
    *(uint4*)&xb[i] = pk.v;
  }
}

// ---------- fused QKV GEMM, 128x128 tiles, m97 staging + xor-swizzle ----------
// Swizzle: 16B block at logical slot s of row r stored at physical slot s^(r&7)
// (via permuted per-lane GLOBAL source; LDS dest stays lane*16). Frag reads at
// ((h*4+fq)^(fr&7)) -> 8 dwords/bank = b128 minimum. Epilogue role-swap kept.
__global__ __launch_bounds__(256) void qkv_gemm_kernel(const u16* __restrict__ xb,
    const u16* __restrict__ Wt, u16* __restrict__ Q, u16* __restrict__ K,
    u16* __restrict__ Vt, const void* __restrict__ x) {
  bool f32m = probe_f32((const u16*)x);
  const u16* xsrc = f32m ? xb : (const u16*)x;   // bf16 mode: stage x directly
  int m0 = blockIdx.x * 128;                 // x rows (s-dim)
  int n0 = blockIdx.y * 128;                 // Wt rows (e/u-dim)
  int w = (int)(blockIdx.y >> 3);            // 0..7 Q, 8..15 K, 16..23 V
  const u16 *Ap, *Bp; int a0, b0;
  if (w == 2) { Ap = xsrc; a0 = m0; Bp = Wt; b0 = n0; }
  else        { Ap = Wt; a0 = n0; Bp = xsrc; b0 = m0; }
  int t = threadIdx.x;
  int wv = t >> 6, l = t & 63;
  int fr = l & 15, fq = l >> 4;
  int wI = (wv >> 1) * 64, wJ = (wv & 1) * 64;
  __shared__ __align__(16) u16 As[128][64];
  __shared__ __align__(16) u16 Bs[128][64];
  int srow = l >> 3;
  int scol = (((l & 7) ^ srow)) * 8;         // swizzled global slot for this lane
  int dcol = (l & 7) * 8;                    // physical LDS col (= lane*16 layout)
  int sw = fr & 7;
  f32x4 acc[4][4];
#pragma unroll
  for (int ii = 0; ii < 4; ++ii)
#pragma unroll
    for (int jj = 0; jj < 4; ++jj)
      for (int i = 0; i < 4; ++i) acc[ii][jj][i] = 0.f;

  for (int kb = 0; kb < kD / 64; ++kb) {
    int k0 = kb * 64;
    __syncthreads();
#pragma unroll
    for (int j = 0; j < 4; ++j) {
      int row = (wv * 4 + j) * 8 + srow;
      gld16(&As[row][dcol], &Ap[(size_t)(a0 + row) * kD + k0 + scol]);
      gld16(&Bs[row][dcol], &Bp[(size_t)(b0 + row) * kD + k0 + scol]);
    }
    __syncthreads();
    bf16x8 af[4][2], bg[4][2];
#pragma unroll
    for (int ii = 0; ii < 4; ++ii) {
      af[ii][0] = *(const bf16x8*)&As[wI + ii * 16 + fr][((0 + fq) ^ sw) * 8];
      af[ii][1] = *(const bf16x8*)&As[wI + ii * 16 + fr][((4 + fq) ^ sw) * 8];
    }
#pragma unroll
    for (int jj = 0; jj < 4; ++jj) {
      bg[jj][0] = *(const bf16x8*)&Bs[wJ + jj * 16 + fr][((0 + fq) ^ sw) * 8];
      bg[jj][1] = *(const bf16x8*)&Bs[wJ + jj * 16 + fr][((4 + fq) ^ sw) * 8];
    }
#pragma unroll
    for (int ii = 0; ii < 4; ++ii)
#pragma unroll
      for (int jj = 0; jj < 4; ++jj) {
        acc[ii][jj] = mfma16(af[ii][0], bg[jj][0], acc[ii][jj]);
        acc[ii][jj] = mfma16(af[ii][1], bg[jj][1], acc[ii][jj]);
      }
  }

  if (w == 2) {
    // I = s (regs), J = e (lanes): Vt[bh][e][s] packed along s
    int uh = wv & 1;
    int u = 2 * blockIdx.y + uh;
    int h = u & 15;
#pragma unroll
    for (int jj = 0; jj < 4; ++jj) {
      int e = jj * 16 + fr;
#pragma unroll
      for (int ii = 0; ii < 4; ++ii) {
        int m = m0 + wI + ii * 16 + fq * 4;
        int b = m >> 11, s0 = m & 2047;
        int bh = b * 16 + h;
        *(bf16x4*)&Vt[((size_t)bh * kHD + e) * kS + s0] =
            __builtin_convertvector(acc[ii][jj], bf16x4);
      }
    }
  } else {
    // I = e (regs), J = s (lanes): Q/K[bh][s][e] packed along e
    int uh = wv >> 1;
    int u = 2 * blockIdx.y + uh;
    int h = u & 15;
    bool isQ = (w == 0);
    u16* dst = isQ ? Q : K;
#pragma unroll
    for (int jj = 0; jj < 4; ++jj) {
      int m = m0 + wJ + jj * 16 + fr;
      int b = m >> 11, s = m & 2047;
      int bh = b * 16 + h;
      size_t rowb = ((size_t)bh * kS + s) * kHD;
#pragma unroll
      for (int ii = 0; ii < 4; ++ii) {
        int e0 = ii * 16 + fq * 4;
        f32x4 v = acc[ii][jj];
        if (isQ) v *= kQScale;
        *(bf16x4*)&dst[rowb + e0] = __builtin_convertvector(v, bf16x4);
      }
    }
  }
}

// ---------- flash attention: 32q/wave, 2-wave blocks, split-K, 6 blocks/CU ----------
// R13: R10/R11/R12 all plateau at ~45us -- occupancy is not LDS-capped (R12:
// 24KB, occupancy unchanged) and the chain length is not the limit (R11).
// The remaining lever: per-query work on the ~55-65%-loaded LDS/VALU pipes.
// R9's 32q/wave halves K/V LDS reads per query but was confounded by a
// 512-block grid (2 blocks/CU, grid-starved). Here: 64q blocks of 2 waves
// (32q/wave, two 16-row groups per wave) x the SAME 1536-chunk split tables
// as R11 -> 6 blocks/CU x 2 waves = 12 waves/CU, all resident at t=0, chain
// <=17 tiles. Each K/V fragment read feeds 4 MFMAs (2 groups x 2) instead of
// 2; per-query LDS cycles drop ~40%; per-wave ILP doubles. LDS stays 24KB
// (single-buffer K/V + Ps[2][2][16][64]). Same slot layout + combine kernel.
static __device__ const signed char kQtab[48] = {
  15,31,30,31,
  14,29,28,30,29,
  13,27,26,28,27,
  12,25,24,26,25,
  11,23,22,24,23,
  10,21,20,22,21,
   9,19,18,20,19,
   8,17,16,18,17,
   7,16,
   6,5,4,3,2,1,0};
static __device__ const signed char kPtab[48] = {
  2,0,0,1,
  2,0,0,1,1,
  2,0,0,1,1,
  2,0,0,1,1,
  2,0,0,1,1,
  2,0,0,1,1,
  2,0,0,1,1,
  2,0,0,1,1,
  2,1,
  2,2,2,2,2,2,2};

__global__ __launch_bounds__(128) void attn_kernel(const u16* __restrict__ Q,
    const u16* __restrict__ K, const u16* __restrict__ Vt, u16* __restrict__ cat,
    float* __restrict__ Po, float* __restrict__ Pl, int split) {
  int bh = (int)(blockIdx.x & 31);
  int c  = (int)(blockIdx.x >> 5);
  int qb, part;
  if (split) { qb = kQtab[c]; part = kPtab[c]; }
  else       { qb = 31 - c;   part = 2; }
  int h0 = (qb + 2) >> 1;
  int tbeg = (part == 1) ? h0 : 0;
  int tend = (part == 0) ? h0 - 1 : qb;
  int q0 = qb * 64;
  int t = threadIdx.x;
  int wv = t >> 6, l = t & 63;
  int fr = l & 15, fq = l >> 4;
  __shared__ __align__(16) u16 Ks[64][64];
  __shared__ __align__(16) u16 Vs[64][64];
  __shared__ __align__(16) u16 Ps[2][2][16][64];
  const u16* Qb = Q + (size_t)bh * kS * kHD;
  const u16* Kb = K + (size_t)bh * kS * kHD;
  const u16* Vb = Vt + (size_t)bh * kHD * kS;

  // each wave owns 32 q rows: two 16-row groups
  int qrow[2];
  bf16x8 qf[2][2];
#pragma unroll
  for (int g = 0; g < 2; ++g) {
    qrow[g] = q0 + wv * 32 + g * 16 + fr;
    qf[g][0] = *(const bf16x8*)&Qb[(size_t)qrow[g] * kHD + fq * 8];
    qf[g][1] = *(const bf16x8*)&Qb[(size_t)qrow[g] * kHD + 32 + fq * 8];
  }

  f32x4 O[2][4];
#pragma unroll
  for (int g = 0; g < 2; ++g)
#pragma unroll
    for (int nt = 0; nt < 4; ++nt)
      for (int i = 0; i < 4; ++i) O[g][nt][i] = 0.f;
  float lsum[2] = {0.f, 0.f};

  // staging with 128 lanes: lane t stages rows (t>>3)+{0,16,32,48}, one 16B
  // chunk each, per array. LDS dest linear; source col carries xor-swizzle
  // (row&7 == (t>>3)&7 for all four rows -> one scol per lane).
  int jr = t >> 3;                            // 0..15
  int dcol = (t & 7) * 8;                     // physical LDS col
  int scol = ((t & 7) ^ (jr & 7)) * 8;        // swizzled global col
  int sw = fr & 7;

  // prologue: stage first tile (barrier drains vmcnt)
  {
    int tb = tbeg * 64;
#pragma unroll
    for (int k = 0; k < 4; ++k) {
      int r = jr + k * 16;
      gld16(&Ks[r][dcol], &Kb[(size_t)(tb + r) * kHD + scol]);
      gld16(&Vs[r][dcol], &Vb[(size_t)r * kS + tb + scol]);
    }
  }
  __syncthreads();

  for (int tt = tbeg; tt <= tend; ++tt) {
    int t0 = tt * 64;
    // S^T = K·Q^T, both groups per K-fragment read
    f32x4 sc[2][4];
    __builtin_amdgcn_s_setprio(1);
#pragma unroll
    for (int nt = 0; nt < 4; ++nt) {
      bf16x8 a0 = *(const bf16x8*)&Ks[nt * 16 + fr][((0 + fq) ^ sw) * 8];
      bf16x8 a1 = *(const bf16x8*)&Ks[nt * 16 + fr][((4 + fq) ^ sw) * 8];
#pragma unroll
      for (int g = 0; g < 2; ++g) {
        f32x4 z; z[0] = z[1] = z[2] = z[3] = 0.f;
        z = mfma16(a0, qf[g][0], z);
        z = mfma16(a1, qf[g][1], z);
        sc[g][nt] = z;
      }
    }
    __builtin_amdgcn_s_setprio(0);
    if (tt == qb) {                           // diagonal tile: mask t > q
#pragma unroll
      for (int g = 0; g < 2; ++g)
#pragma unroll
        for (int nt = 0; nt < 4; ++nt)
#pragma unroll
          for (int r = 0; r < 4; ++r)
            if (t0 + nt * 16 + fq * 4 + r > qrow[g]) sc[g][nt][r] = -__builtin_inff();
    }
#pragma unroll
    for (int g = 0; g < 2; ++g)
#pragma unroll
      for (int nt = 0; nt < 4; ++nt) {
#pragma unroll
        for (int r = 0; r < 4; ++r) {
          float p = exp2f(sc[g][nt][r]);      // Q pre-scaled by scale*log2e
          sc[g][nt][r] = p;
          lsum[g] += p;
        }
        // logical 16B unit nt*2+(fq>>1), half fq&1 -> physical unit ^ (fr&7)
        *(bf16x4*)&Ps[wv][g][fr][(((nt * 2 + (fq >> 1)) ^ sw) * 8) + (fq & 1) * 4] =
            __builtin_convertvector(sc[g][nt], bf16x4);
      }
    // O^T += V^T · P^T  (per-wave Ps; compiler inserts lgkmcnt)
    bf16x8 pf[2][2];
#pragma unroll
    for (int g = 0; g < 2; ++g) {
      pf[g][0] = *(const bf16x8*)&Ps[wv][g][fr][(fq ^ sw) * 8];
      pf[g][1] = *(const bf16x8*)&Ps[wv][g][fr][((4 + fq) ^ sw) * 8];
    }
    __builtin_amdgcn_s_setprio(1);
#pragma unroll
    for (int nt = 0; nt < 4; ++nt) {
      bf16x8 v0 = *(const bf16x8*)&Vs[nt * 16 + fr][((0 + fq) ^ sw) * 8];
      bf16x8 v1 = *(const bf16x8*)&Vs[nt * 16 + fr][((4 + fq) ^ sw) * 8];
#pragma unroll
      for (int g = 0; g < 2; ++g) {
        O[g][nt] = mfma16(v0, pf[g][0], O[g][nt]);
        O[g][nt] = mfma16(v1, pf[g][1], O[g][nt]);
      }
    }
    __builtin_amdgcn_s_setprio(0);
    if (tt < tend) {
      __syncthreads();                        // all waves done reading Ks/Vs
      int t0n = t0 + 64;
#pragma unroll
      for (int k = 0; k < 4; ++k) {
        int r = jr + k * 16;
        gld16(&Ks[r][dcol], &Kb[(size_t)(t0n + r) * kHD + scol]);
        gld16(&Vs[r][dcol], &Vb[(size_t)r * kS + t0n + scol]);
      }
      __syncthreads();                        // drains vmcnt: next tile ready
    }
  }
#pragma unroll
  for (int g = 0; g < 2; ++g) {
    lsum[g] += __shfl_xor(lsum[g], 16, 64);
    lsum[g] += __shfl_xor(lsum[g], 32, 64);
  }
  if (part == 2) {
    int b = bh >> 4, h = bh & 15;
#pragma unroll
    for (int g = 0; g < 2; ++g) {
      float inv = 1.0f / lsum[g];
      size_t rowbase = ((size_t)(b * kS + qrow[g])) * kD + h * kHD;
#pragma unroll
      for (int nt = 0; nt < 4; ++nt) {
        f32x4 ov = O[g][nt] * inv;
        *(bf16x4*)&cat[rowbase + nt * 16 + fq * 4] = __builtin_convertvector(ov, bf16x4);
      }
    }
  } else {
    // split level: write raw partials (private slot, no atomics)
    int slot = ((bh << 4) + (qb - 16)) * 2 + part;
#pragma unroll
    for (int g = 0; g < 2; ++g) {
      int q = wv * 32 + g * 16 + fr;
      float* Pb = Po + (size_t)slot * 4096 + q * 64;
      if (fq == 0) Pl[slot * 64 + q] = lsum[g];
#pragma unroll
      for (int nt = 0; nt < 4; ++nt)
        *(f32x4*)&Pb[nt * 16 + fq * 4] = O[g][nt];
    }
  }
}

// ---------- split-K combine: cat[q>=1024] = (O_p0 + O_p1) / (l_p0 + l_p1) ----------
__global__ __launch_bounds__(256) void attn_combine_kernel(
    const float* __restrict__ Po, const float* __restrict__ Pl,
    u16* __restrict__ cat) {
  int bh = (int)(blockIdx.x >> 4);            // 0..31
  int lvl = (int)(blockIdx.x & 15);           // qb = lvl + 16
  int t = threadIdx.x;
  int slot = ((bh << 4) + lvl) * 2;
  int b = bh >> 4, h = bh & 15;
  int e0 = (t & 15) * 4;
  for (int qq = 0; qq < 64; qq += 16) {
    int q = qq + (t >> 4);
    const float* A = Po + (size_t)slot * 4096 + q * 64 + e0;
    float l = Pl[slot * 64 + q] + Pl[(slot + 1) * 64 + q];
    float inv = 1.0f / l;
    f32x4 a = *(const f32x4*)A;
    f32x4 bv = *(const f32x4*)(A + 4096);
    f32x4 v = (a + bv) * inv;
    int qrow = (lvl + 16) * 64 + q;
    *(bf16x4*)&cat[((size_t)(b * kS + qrow)) * kD + h * kHD + e0] =
        __builtin_convertvector(v, bf16x4);
  }
}

// ---------- out projection: 64(m)x128(n) tiles -> 512 blocks (2/CU) ----------
// A=Wp (n in regs -> packed stores), B=cat (m in lanes). Swizzled m97 staging.
// bf16 mode: stages Wp directly (row-major [n][k] already).
__global__ __launch_bounds__(256) void out_gemm_kernel(const u16* __restrict__ cat,
    const u16* __restrict__ Wpb, const void* __restrict__ Wp,
    const void* __restrict__ bp, void* __restrict__ out,
    const void* __restrict__ x) {
  bool f32m = probe_f32((const u16*)x);
  const u16* wsrc = f32m ? Wpb : (const u16*)Wp;
  int m0 = blockIdx.x * 64;
  int n0 = blockIdx.y * 128;
  int t = threadIdx.x;
  int wv = t >> 6, l = t & 63;
  int fr = l & 15, fq = l >> 4;
  int wI = (wv >> 1) * 64, wJ = (wv & 1) * 32;
  __shared__ __align__(16) u16 As[128][64];   // Wp rows (n)
  __shared__ __align__(16) u16 Bs[64][64];    // cat rows (m)
  int srow = l >> 3;
  int scol = (((l & 7) ^ srow)) * 8;
  int dcol = (l & 7) * 8;
  int sw = fr & 7;
  f32x4 acc[4][2];
#pragma unroll
  for (int ii = 0; ii < 4; ++ii)
#pragma unroll
    for (int jj = 0; jj < 2; ++jj)
      for (int i = 0; i < 4; ++i) acc[ii][jj][i] = 0.f;

  for (int kb = 0; kb < kD / 64; ++kb) {
    int k0 = kb * 64;
    __syncthreads();
#pragma unroll
    for (int j = 0; j < 4; ++j) {
      int row = j * 32 + wv * 8 + srow;
      gld16(&As[row][dcol], &wsrc[(size_t)(n0 + row) * kD + k0 + scol]);
    }
#pragma unroll
    for (int j = 0; j < 2; ++j) {
      int row = j * 32 + wv * 8 + srow;
      gld16(&Bs[row][dcol], &cat[(size_t)(m0 + row) * kD + k0 + scol]);
    }
    __syncthreads();
    bf16x8 af[4][2], bg[2][2];
#pragma unroll
    for (int ii = 0; ii < 4; ++ii) {
      af[ii][0] = *(const bf16x8*)&As[wI + ii * 16 + fr][((0 + fq) ^ sw) * 8];
      af[ii][1] = *(const bf16x8*)&As[wI + ii * 16 + fr][((4 + fq) ^ sw) * 8];
    }
#pragma unroll
    for (int jj = 0; jj < 2; ++jj) {
      bg[jj][0] = *(const bf16x8*)&Bs[wJ + jj * 16 + fr][((0 + fq) ^ sw) * 8];
      bg[jj][1] = *(const bf16x8*)&Bs[wJ + jj * 16 + fr][((4 + fq) ^ sw) * 8];
    }
#pragma unroll
    for (int ii = 0; ii < 4; ++ii)
#pragma unroll
      for (int jj = 0; jj < 2; ++jj) {
        acc[ii][jj] = mfma16(af[ii][0], bg[jj][0], acc[ii][jj]);
        acc[ii][jj] = mfma16(af[ii][1], bg[jj][1], acc[ii][jj]);
      }
  }
  const float* bpf = (const float*)bp;
  const u16*   bpb = (const u16*)bp;
#pragma unroll
  for (int ii = 0; ii < 4; ++ii) {
    int n = n0 + wI + ii * 16 + fq * 4;       // 4 consecutive n in regs
    f32x4 bias;
    if (f32m) bias = *(const f32x4*)&bpf[n];
    else { bias[0] = bf2f(bpb[n]); bias[1] = bf2f(bpb[n + 1]);
           bias[2] = bf2f(bpb[n + 2]); bias[3] = bf2f(bpb[n + 3]); }
#pragma unroll
    for (int jj = 0; jj < 2; ++jj) {
      int m = m0 + wJ + jj * 16 + fr;
      f32x4 v = acc[ii][jj] + bias;
      if (f32m) *(f32x4*)&((float*)out)[(size_t)m * kD + n] = v;
      else      *(bf16x4*)&((u16*)out)[(size_t)m * kD + n] = __builtin_convertvector(v, bf16x4);
    }
  }
}

extern "C" void kernel_launch(void* const* d_in, const int* in_sizes, int n_in,
                              void* d_out, int out_size, void* d_ws, size_t ws_size,
                              hipStream_t stream) {
  const void* x  = d_in[0];
  const void* Wq = d_in[1];
  const void* Wk = d_in[2];
  const void* Wv = d_in[3];
  const void* Wp = d_in[4];
  const void* bp = d_in[5];

  char* ws = (char*)d_ws;
  u16* Wt  = (u16*)(ws + 256);                        // 3072*1024*2 = 6291456 B
  u16* Wpb = (u16*)(ws + 256 + 6291456);              // 1024*1024*2 = 2097152 B
  u16* Qp  = (u16*)(ws + 256 + 6291456 + 2097152);    // 32*2048*64*2 = 8388608 B each
  u16* Kp  = Qp  + (size_t)32 * 2048 * 64;
  u16* Vtp = Kp  + (size_t)32 * 2048 * 64;
  u16* xb  = Vtp + (size_t)32 * 2048 * 64;            // aliased: xb (pre-attn) == cat (post-attn)
  u16* cat = xb;
  // split-K partials: 32bh x 16lvl x 2 parts x (64q x 64e f32)  = 16.78 MB
  //                   + lsum 32x16x2x64 f32                     =  0.26 MB
  size_t poOff = 256 + 6291456 + 2097152 + (size_t)4 * 8388608;  // 41,943,296
  size_t plOff = poOff + (size_t)32 * 16 * 2 * 4096 * 4;
  size_t needWs = plOff + (size_t)32 * 16 * 2 * 64 * 4;
  int split = (ws_size >= needWs) ? 1 : 0;
  float* Po = (float*)(ws + poOff);
  float* Pl = (float*)(ws + plOff);

  cast_all_kernel<<<3840, 256, 0, stream>>>(Wq, Wk, Wv, Wp, x, Wt, Wpb, xb);
  qkv_gemm_kernel<<<dim3(32, 24), 256, 0, stream>>>(xb, Wt, Qp, Kp, Vtp, x);
  attn_kernel<<<split ? 1536 : 1024, 128, 0, stream>>>(Qp, Kp, Vtp, cat, Po, Pl, split);
  if (split)
    attn_combine_kernel<<<512, 256, 0, stream>>>(Po, Pl, cat);
  out_gemm_kernel<<<dim3(64, 8), 256, 0, stream>>>(cat, Wpb, Wp, bp, d_out, x);
}

// Round 7
// 172.705 us; speedup vs baseline: 1.0782x; 1.0782x over previous
//
#include <hip/hip_runtime.h>

typedef __bf16 bf16x8 __attribute__((ext_vector_type(8)));
typedef __bf16 bf16x4 __attribute__((ext_vector_type(4)));
typedef float f32x4 __attribute__((ext_vector_type(4)));
typedef unsigned short u16;
typedef unsigned int u32;

static constexpr int kS = 2048, kD = 1024, kHD = 64;
// softmax scale (D^-0.5 = 1/32) * log2(e), folded into Q at projection time
static constexpr float kQScale = 0.03125f * 1.44269504f;

__device__ __forceinline__ u16 f2bf(float f) {
  union { float f; u32 u; } v; v.f = f;
  u32 r = v.u + 0x7FFFu + ((v.u >> 16) & 1u);
  return (u16)(r >> 16);
}
__device__ __forceinline__ float bf2f(u16 u) {
  union { u32 u; float f; } v; v.u = ((u32)u) << 16;
  return v.f;
}
__device__ __forceinline__ u32 pk2(float a, float b) {
  return (u32)f2bf(a) | ((u32)f2bf(b) << 16);
}
__device__ __forceinline__ f32x4 mfma16(bf16x8 a, bf16x8 b, f32x4 c) {
  return __builtin_amdgcn_mfma_f32_16x16x32_bf16(a, b, c, 0, 0, 0);
}
// async global->LDS, 16B per lane (m97 rung). LDS dest is wave-uniform base +
// lane*16 (UNPADDED [rows][64]); the GLOBAL source per lane is free, which is
// where the xor-swizzle (and now the K row-permute) lives.
__device__ __forceinline__ void gld16(u16* lds, const u16* g) {
  __builtin_amdgcn_global_load_lds(
      (const __attribute__((address_space(1))) u32*)g,
      (__attribute__((address_space(3))) u32*)lds, 16, 0, 0);
}

// inline dtype probe: 256 samples of x as u16. fp32 bit patterns: the low-
// mantissa halves have uniform exponent fields -> ~47% read as |bf16|>=128;
// bf16 N(0,1) data: none. One load + one syncthreads_count per block.
__device__ __forceinline__ bool probe_f32(const u16* __restrict__ xr) {
  int ex = (xr[threadIdx.x] >> 7) & 0xFF;
  int n = __syncthreads_count(ex >= 134);
  return n > 8;
}

union Pack8 { u16 u[8]; uint4 v; };

// ---------- merged cast: Wt transpose always; Wp/x cast only in fp32 mode ----------
// bf16 mode: x and Wp are already in the exact layout the GEMMs stage from ->
// blocks 768+ exit (qkv/out read the originals directly; saves ~36MB r/w).
__global__ void cast_all_kernel(const void* Wq, const void* Wk, const void* Wv,
                                const void* Wp, const void* x,
                                u16* __restrict__ Wt, u16* __restrict__ Wpb,
                                u16* __restrict__ xb) {
  bool f32m = probe_f32((const u16*)x);
  int bid = blockIdx.x;
  int t = threadIdx.x;
  __shared__ float Ts[64][65];
  if (bid < 768) {
    // ---- W[h][d][e] -> Wt[(u*64+e)][d], u = which*16 + h ----
    int u = bid >> 4;
    int d0 = (bid & 15) * 64;
    int w = u >> 4, h = u & 15;
    const void* srcv = (w == 0) ? Wq : (w == 1) ? Wk : Wv;
    const float* sf = (const float*)srcv + (size_t)h * kD * kHD;
    const u16*   sb = (const u16*)srcv + (size_t)h * kD * kHD;
    int row = t >> 4;
    int c4 = (t & 15) * 4;
    for (int rr = 0; rr < 64; rr += 16) {
      int r = rr + row;
      if (f32m) {
        float4 v = *(const float4*)&sf[(size_t)(d0 + r) * kHD + c4];
        Ts[r][c4 + 0] = v.x; Ts[r][c4 + 1] = v.y; Ts[r][c4 + 2] = v.z; Ts[r][c4 + 3] = v.w;
      } else {
        const u16* p = &sb[(size_t)(d0 + r) * kHD + c4];
        Ts[r][c4 + 0] = bf2f(p[0]); Ts[r][c4 + 1] = bf2f(p[1]);
        Ts[r][c4 + 2] = bf2f(p[2]); Ts[r][c4 + 3] = bf2f(p[3]);
      }
    }
    __syncthreads();
    for (int rr = 0; rr < 64; rr += 16) {
      int e = rr + row;
      uint2 pk;
      pk.x = pk2(Ts[c4 + 0][e], Ts[c4 + 1][e]);
      pk.y = pk2(Ts[c4 + 2][e], Ts[c4 + 3][e]);
      *(uint2*)&Wt[(size_t)u * (kHD * kD) + (size_t)e * kD + d0 + c4] = pk;
    }
  } else if (bid < 1792) {
    if (!f32m) return;
    int i = ((bid - 768) * 256 + t) * 4;
    float4 v = *(const float4*)((const float*)Wp + i);
    uint2 pk; pk.x = pk2(v.x, v.y); pk.y = pk2(v.z, v.w);
    *(uint2*)&Wpb[i] = pk;
  } else {
    if (!f32m) return;
    size_t i = ((size_t)(bid - 1792) * 256 + t) * 8;
    const float* xf = (const float*)x;
    float4 a = *(const float4*)&xf[i];
    float4 b = *(const float4*)&xf[i + 4];
    Pack8 pk;
    pk.u[0] = f2bf(a.x); pk.u[1] = f2bf(a.y); pk.u[2] = f2bf(a.z); pk.u[3] = f2bf(a.w);
    pk.u[4] = f2bf(b.x); pk.u[5] = f2bf(b.y); pk.u[6] = f2bf(b.z); pk.u[7] = f2bf(b.w);
    *(uint4*)&xb[i] = pk.v;
  }
}

// ---------- fused QKV GEMM, 128x128 tiles, m97 staging + xor-swizzle ----------
// Swizzle: 16B block at logical slot s of row r stored at physical slot s^(r&7)
// (via permuted per-lane GLOBAL source; LDS dest stays lane*16). Frag reads at
// ((h*4+fq)^(fr&7)) -> 8 dwords/bank = b128 minimum. Epilogue role-swap kept.
__global__ __launch_bounds__(256) void qkv_gemm_kernel(const u16* __restrict__ xb,
    const u16* __restrict__ Wt, u16* __restrict__ Q, u16* __restrict__ K,
    u16* __restrict__ Vt, const void* __restrict__ x) {
  bool f32m = probe_f32((const u16*)x);
  const u16* xsrc = f32m ? xb : (const u16*)x;   // bf16 mode: stage x directly
  int m0 = blockIdx.x * 128;                 // x rows (s-dim)
  int n0 = blockIdx.y * 128;                 // Wt rows (e/u-dim)
  int w = (int)(blockIdx.y >> 3);            // 0..7 Q, 8..15 K, 16..23 V
  const u16 *Ap, *Bp; int a0, b0;
  if (w == 2) { Ap = xsrc; a0 = m0; Bp = Wt; b0 = n0; }
  else        { Ap = Wt; a0 = n0; Bp = xsrc; b0 = m0; }
  int t = threadIdx.x;
  int wv = t >> 6, l = t & 63;
  int fr = l & 15, fq = l >> 4;
  int wI = (wv >> 1) * 64, wJ = (wv & 1) * 64;
  __shared__ __align__(16) u16 As[128][64];
  __shared__ __align__(16) u16 Bs[128][64];
  int srow = l >> 3;
  int scol = (((l & 7) ^ srow)) * 8;         // swizzled global slot for this lane
  int dcol = (l & 7) * 8;                    // physical LDS col (= lane*16 layout)
  int sw = fr & 7;
  f32x4 acc[4][4];
#pragma unroll
  for (int ii = 0; ii < 4; ++ii)
#pragma unroll
    for (int jj = 0; jj < 4; ++jj)
      for (int i = 0; i < 4; ++i) acc[ii][jj][i] = 0.f;

  for (int kb = 0; kb < kD / 64; ++kb) {
    int k0 = kb * 64;
    __syncthreads();
#pragma unroll
    for (int j = 0; j < 4; ++j) {
      int row = (wv * 4 + j) * 8 + srow;
      gld16(&As[row][dcol], &Ap[(size_t)(a0 + row) * kD + k0 + scol]);
      gld16(&Bs[row][dcol], &Bp[(size_t)(b0 + row) * kD + k0 + scol]);
    }
    __syncthreads();
    bf16x8 af[4][2], bg[4][2];
#pragma unroll
    for (int ii = 0; ii < 4; ++ii) {
      af[ii][0] = *(const bf16x8*)&As[wI + ii * 16 + fr][((0 + fq) ^ sw) * 8];
      af[ii][1] = *(const bf16x8*)&As[wI + ii * 16 + fr][((4 + fq) ^ sw) * 8];
    }
#pragma unroll
    for (int jj = 0; jj < 4; ++jj) {
      bg[jj][0] = *(const bf16x8*)&Bs[wJ + jj * 16 + fr][((0 + fq) ^ sw) * 8];
      bg[jj][1] = *(const bf16x8*)&Bs[wJ + jj * 16 + fr][((4 + fq) ^ sw) * 8];
    }
#pragma unroll
    for (int ii = 0; ii < 4; ++ii)
#pragma unroll
      for (int jj = 0; jj < 4; ++jj) {
        acc[ii][jj] = mfma16(af[ii][0], bg[jj][0], acc[ii][jj]);
        acc[ii][jj] = mfma16(af[ii][1], bg[jj][1], acc[ii][jj]);
      }
  }

  if (w == 2) {
    // I = s (regs), J = e (lanes): Vt[bh][e][s] packed along s
    int uh = wv & 1;
    int u = 2 * blockIdx.y + uh;
    int h = u & 15;
#pragma unroll
    for (int jj = 0; jj < 4; ++jj) {
      int e = jj * 16 + fr;
#pragma unroll
      for (int ii = 0; ii < 4; ++ii) {
        int m = m0 + wI + ii * 16 + fq * 4;
        int b = m >> 11, s0 = m & 2047;
        int bh = b * 16 + h;
        *(bf16x4*)&Vt[((size_t)bh * kHD + e) * kS + s0] =
            __builtin_convertvector(acc[ii][jj], bf16x4);
      }
    }
  } else {
    // I = e (regs), J = s (lanes): Q/K[bh][s][e] packed along e
    int uh = wv >> 1;
    int u = 2 * blockIdx.y + uh;
    int h = u & 15;
    bool isQ = (w == 0);
    u16* dst = isQ ? Q : K;
#pragma unroll
    for (int jj = 0; jj < 4; ++jj) {
      int m = m0 + wJ + jj * 16 + fr;
      int b = m >> 11, s = m & 2047;
      int bh = b * 16 + h;
      size_t rowb = ((size_t)bh * kS + s) * kHD;
#pragma unroll
      for (int ii = 0; ii < 4; ++ii) {
        int e0 = ii * 16 + fq * 4;
        f32x4 v = acc[ii][jj];
        if (isQ) v *= kQScale;
        *(bf16x4*)&dst[rowb + e0] = __builtin_convertvector(v, bf16x4);
      }
    }
  }
}

// ---------- flash attention: P-in-register via K-row-permuted LDS ----------
// R14: R9-R13 showed the kernel is bound by each wave's serial per-iter chain
// (ds_read K -> QK -> exp2 -> Ps write -> lgkmcnt -> Ps read -> PV), with ~16
// waves/CU sufficient to cover it (more capacity: no gain; fewer: big loss).
// This round removes the Ps LDS round-trip entirely. QK^T puts P[q][k] at
// lane(fr=q) in k-groups 4fq+r; PV's B-operand wants k-groups 8fq+j. Fix: a
// bijective K-row PERMUTATION in LDS, sigma(R) = 8*((R>>2)&3)+4*((R>>4)&1)
// +32*(R>>5)+(R&3), folded into the DMA's per-lane global source row (zero
// instructions -- same trick as the col xor-swizzle). Then sc[nt][r] at lane
// fq IS P[q][k=8fq+4(nt&1)+32(nt>>1)+r]: pf0/pf1 are built by 8 local cvt_pk,
// no ds_write/ds_read/lgkmcnt, no Ps buffer (LDS 40->32KB). Diagonal mask
// uses the permuted-k formula. Structure otherwise = R10 (1024 blocks = 4/CU
// all-resident, dbuf K/V DMA, 1 barrier/iter, setprio around MFMA).
__global__ __launch_bounds__(256) void attn_kernel(const u16* __restrict__ Q,
    const u16* __restrict__ K, const u16* __restrict__ Vt, u16* __restrict__ cat) {
  int qb = 31 - (int)(blockIdx.x >> 5);       // heavy (late-q) blocks dispatch first
  int bh = (int)(blockIdx.x & 31);
  int q0 = qb * 64;
  int t = threadIdx.x;
  int wv = t >> 6, l = t & 63;
  int fr = l & 15, fq = l >> 4;
  __shared__ __align__(16) u16 Ks[2][64][64];
  __shared__ __align__(16) u16 Vs[2][64][64];
  const u16* Qb = Q + (size_t)bh * kS * kHD;
  const u16* Kb = K + (size_t)bh * kS * kHD;
  const u16* Vb = Vt + (size_t)bh * kHD * kS;

  int qrow = q0 + wv * 16 + fr;
  bf16x8 qf0 = *(const bf16x8*)&Qb[(size_t)qrow * kHD + fq * 8];
  bf16x8 qf1 = *(const bf16x8*)&Qb[(size_t)qrow * kHD + 32 + fq * 8];

  f32x4 O[4];
#pragma unroll
  for (int nt = 0; nt < 4; ++nt) for (int i = 0; i < 4; ++i) O[nt][i] = 0.f;
  float lsum = 0.f;

  // staging geometry: wave wv owns LDS rows wv*16 + {0..15}; each lane DMAs
  // two 16B chunks per tile per array. LDS dest linear (lane*16); the GLOBAL
  // source carries (a) the col xor-swizzle and (b) for K, the row permutation
  // sigma so that QK^T output lands in PV's B-fragment k-order.
  int jr = l >> 3;                            // 0..7
  int dcol = (l & 7) * 8;                     // physical LDS col
  int scol = ((l & 7) ^ jr) * 8;              // swizzled global col
  int r0 = wv * 16 + jr;                      // LDS rows this lane stages
  int r1 = r0 + 8;                            // (r&7 == jr for both)
  // permuted global K rows for LDS rows r0/r1
  int gk0 = 8 * ((r0 >> 2) & 3) + 4 * ((r0 >> 4) & 1) + 32 * (r0 >> 5) + (r0 & 3);
  int gk1 = 8 * ((r1 >> 2) & 3) + 4 * ((r1 >> 4) & 1) + 32 * (r1 >> 5) + (r1 & 3);
  int sw = fr & 7;

  // prologue: stage tile 0 into buffer 0 (barrier drains vmcnt)
  gld16(&Ks[0][r0][dcol], &Kb[(size_t)gk0 * kHD + scol]);
  gld16(&Ks[0][r1][dcol], &Kb[(size_t)gk1 * kHD + scol]);
  gld16(&Vs[0][r0][dcol], &Vb[(size_t)r0 * kS + scol]);
  gld16(&Vs[0][r1][dcol], &Vb[(size_t)r1 * kS + scol]);
  __syncthreads();

  int cur = 0;
  for (int tt = 0; tt <= qb; ++tt) {
    int t0 = tt * 64;
    if (tt < qb) {                            // async-stage next tile under compute
      int t0n = t0 + 64;
      gld16(&Ks[cur ^ 1][r0][dcol], &Kb[(size_t)(t0n + gk0) * kHD + scol]);
      gld16(&Ks[cur ^ 1][r1][dcol], &Kb[(size_t)(t0n + gk1) * kHD + scol]);
      gld16(&Vs[cur ^ 1][r0][dcol], &Vb[(size_t)r0 * kS + t0n + scol]);
      gld16(&Vs[cur ^ 1][r1][dcol], &Vb[(size_t)r1 * kS + t0n + scol]);
    }
    // S^T = K·Q^T (K rows permuted: sc[nt][r] = P[q][k=8fq+4(nt&1)+32(nt>>1)+r])
    f32x4 sc[4];
    __builtin_amdgcn_s_setprio(1);
#pragma unroll
    for (int nt = 0; nt < 4; ++nt) {
      f32x4 z; z[0] = z[1] = z[2] = z[3] = 0.f;
      bf16x8 a0 = *(const bf16x8*)&Ks[cur][nt * 16 + fr][((0 + fq) ^ sw) * 8];
      bf16x8 a1 = *(const bf16x8*)&Ks[cur][nt * 16 + fr][((4 + fq) ^ sw) * 8];
      z = mfma16(a0, qf0, z);
      z = mfma16(a1, qf1, z);
      sc[nt] = z;
    }
    __builtin_amdgcn_s_setprio(0);
    if (tt == qb) {                           // diagonal tile: mask k > q (permuted k)
#pragma unroll
      for (int nt = 0; nt < 4; ++nt)
#pragma unroll
        for (int r = 0; r < 4; ++r)
          if (t0 + 8 * fq + 4 * (nt & 1) + 32 * (nt >> 1) + r > qrow)
            sc[nt][r] = -__builtin_inff();
    }
#pragma unroll
    for (int nt = 0; nt < 4; ++nt)
#pragma unroll
      for (int r = 0; r < 4; ++r) {
        float p = exp2f(sc[nt][r]);           // Q pre-scaled by scale*log2e
        sc[nt][r] = p;
        lsum += p;
      }
    // P fragments entirely in-register: pf0 = k 8fq+0..7, pf1 = k 32+8fq+0..7
    union PB { bf16x4 h[2]; bf16x8 v; } pb0, pb1;
    pb0.h[0] = __builtin_convertvector(sc[0], bf16x4);
    pb0.h[1] = __builtin_convertvector(sc[1], bf16x4);
    pb1.h[0] = __builtin_convertvector(sc[2], bf16x4);
    pb1.h[1] = __builtin_convertvector(sc[3], bf16x4);
    // O^T += V^T · P^T
    __builtin_amdgcn_s_setprio(1);
#pragma unroll
    for (int nt = 0; nt < 4; ++nt) {
      bf16x8 v0 = *(const bf16x8*)&Vs[cur][nt * 16 + fr][((0 + fq) ^ sw) * 8];
      bf16x8 v1 = *(const bf16x8*)&Vs[cur][nt * 16 + fr][((4 + fq) ^ sw) * 8];
      O[nt] = mfma16(v0, pb0.v, O[nt]);
      O[nt] = mfma16(v1, pb1.v, O[nt]);
    }
    __builtin_amdgcn_s_setprio(0);
    __syncthreads();                          // drains vmcnt: next tile ready
    cur ^= 1;
  }
  lsum += __shfl_xor(lsum, 16, 64);
  lsum += __shfl_xor(lsum, 32, 64);
  float inv = 1.0f / lsum;
  int b = bh >> 4, h = bh & 15;
  size_t rowbase = ((size_t)(b * kS + qrow)) * kD + h * kHD;
#pragma unroll
  for (int nt = 0; nt < 4; ++nt) {
    f32x4 ov = O[nt] * inv;
    *(bf16x4*)&cat[rowbase + nt * 16 + fq * 4] = __builtin_convertvector(ov, bf16x4);
  }
}

// ---------- out projection: 64(m)x128(n) tiles -> 512 blocks (2/CU) ----------
// A=Wp (n in regs -> packed stores), B=cat (m in lanes). Swizzled m97 staging.
// bf16 mode: stages Wp directly (row-major [n][k] already).
__global__ __launch_bounds__(256) void out_gemm_kernel(const u16* __restrict__ cat,
    const u16* __restrict__ Wpb, const void* __restrict__ Wp,
    const void* __restrict__ bp, void* __restrict__ out,
    const void* __restrict__ x) {
  bool f32m = probe_f32((const u16*)x);
  const u16* wsrc = f32m ? Wpb : (const u16*)Wp;
  int m0 = blockIdx.x * 64;
  int n0 = blockIdx.y * 128;
  int t = threadIdx.x;
  int wv = t >> 6, l = t & 63;
  int fr = l & 15, fq = l >> 4;
  int wI = (wv >> 1) * 64, wJ = (wv & 1) * 32;
  __shared__ __align__(16) u16 As[128][64];   // Wp rows (n)
  __shared__ __align__(16) u16 Bs[64][64];    // cat rows (m)
  int srow = l >> 3;
  int scol = (((l & 7) ^ srow)) * 8;
  int dcol = (l & 7) * 8;
  int sw = fr & 7;
  f32x4 acc[4][2];
#pragma unroll
  for (int ii = 0; ii < 4; ++ii)
#pragma unroll
    for (int jj = 0; jj < 2; ++jj)
      for (int i = 0; i < 4; ++i) acc[ii][jj][i] = 0.f;

  for (int kb = 0; kb < kD / 64; ++kb) {
    int k0 = kb * 64;
    __syncthreads();
#pragma unroll
    for (int j = 0; j < 4; ++j) {
      int row = j * 32 + wv * 8 + srow;
      gld16(&As[row][dcol], &wsrc[(size_t)(n0 + row) * kD + k0 + scol]);
    }
#pragma unroll
    for (int j = 0; j < 2; ++j) {
      int row = j * 32 + wv * 8 + srow;
      gld16(&Bs[row][dcol], &cat[(size_t)(m0 + row) * kD + k0 + scol]);
    }
    __syncthreads();
    bf16x8 af[4][2], bg[2][2];
#pragma unroll
    for (int ii = 0; ii < 4; ++ii) {
      af[ii][0] = *(const bf16x8*)&As[wI + ii * 16 + fr][((0 + fq) ^ sw) * 8];
      af[ii][1] = *(const bf16x8*)&As[wI + ii * 16 + fr][((4 + fq) ^ sw) * 8];
    }
#pragma unroll
    for (int jj = 0; jj < 2; ++jj) {
      bg[jj][0] = *(const bf16x8*)&Bs[wJ + jj * 16 + fr][((0 + fq) ^ sw) * 8];
      bg[jj][1] = *(const bf16x8*)&Bs[wJ + jj * 16 + fr][((4 + fq) ^ sw) * 8];
    }
#pragma unroll
    for (int ii = 0; ii < 4; ++ii)
#pragma unroll
      for (int jj = 0; jj < 2; ++jj) {
        acc[ii][jj] = mfma16(af[ii][0], bg[jj][0], acc[ii][jj]);
        acc[ii][jj] = mfma16(af[ii][1], bg[jj][1], acc[ii][jj]);
      }
  }
  const float* bpf = (const float*)bp;
  const u16*   bpb = (const u16*)bp;
#pragma unroll
  for (int ii = 0; ii < 4; ++ii) {
    int n = n0 + wI + ii * 16 + fq * 4;       // 4 consecutive n in regs
    f32x4 bias;
    if (f32m) bias = *(const f32x4*)&bpf[n];
    else { bias[0] = bf2f(bpb[n]); bias[1] = bf2f(bpb[n + 1]);
           bias[2] = bf2f(bpb[n + 2]); bias[3] = bf2f(bpb[n + 3]); }
#pragma unroll
    for (int jj = 0; jj < 2; ++jj) {
      int m = m0 + wJ + jj * 16 + fr;
      f32x4 v = acc[ii][jj] + bias;
      if (f32m) *(f32x4*)&((float*)out)[(size_t)m * kD + n] = v;
      else      *(bf16x4*)&((u16*)out)[(size_t)m * kD + n] = __builtin_convertvector(v, bf16x4);
    }
  }
}

extern "C" void kernel_launch(void* const* d_in, const int* in_sizes, int n_in,
                              void* d_out, int out_size, void* d_ws, size_t ws_size,
                              hipStream_t stream) {
  const void* x  = d_in[0];
  const void* Wq = d_in[1];
  const void* Wk = d_in[2];
  const void* Wv = d_in[3];
  const void* Wp = d_in[4];
  const void* bp = d_in[5];

  char* ws = (char*)d_ws;
  u16* Wt  = (u16*)(ws + 256);                        // 3072*1024*2 = 6291456 B
  u16* Wpb = (u16*)(ws + 256 + 6291456);              // 1024*1024*2 = 2097152 B
  u16* Qp  = (u16*)(ws + 256 + 6291456 + 2097152);    // 32*2048*64*2 = 8388608 B each
  u16* Kp  = Qp  + (size_t)32 * 2048 * 64;
  u16* Vtp = Kp  + (size_t)32 * 2048 * 64;
  u16* xb  = Vtp + (size_t)32 * 2048 * 64;            // aliased: xb (pre-attn) == cat (post-attn)
  u16* cat = xb;

  cast_all_kernel<<<3840, 256, 0, stream>>>(Wq, Wk, Wv, Wp, x, Wt, Wpb, xb);
  qkv_gemm_kernel<<<dim3(32, 24), 256, 0, stream>>>(xb, Wt, Qp, Kp, Vtp, x);
  attn_kernel<<<1024, 256, 0, stream>>>(Qp, Kp, Vtp, cat);
  out_gemm_kernel<<<dim3(64, 8), 256, 0, stream>>>(cat, Wpb, Wp, bp, d_out, x);
}